// Round 2
// baseline (752.379 us; speedup 1.0000x reference)
//
#include <hip/hip_runtime.h>
#include <hip/hip_bf16.h>
#include <cstdint>

// Readout: logits = W2 . gelu(W1^T [nodes; z_local[batch]; z_meta] + b1) + b2
// nodes@W1_lo via bf16 MFMA (HBM-bound, ~85us floor); z_local@W1_mid + z_meta@W1_hi
// + b1 all folded into pre[B,128] (fp32 exact) by prep.
// Main kernel is persistent: w1f staged to LDS once per block, then each wave
// grid-strides over 16-row strips with a 2-deep register double-buffer and NO
// per-tile barriers (w1s is read-only after the single prologue barrier).

typedef __attribute__((ext_vector_type(8))) __bf16 bf16x8;
typedef __attribute__((ext_vector_type(4))) float f32x4;
typedef __attribute__((address_space(3))) uint32_t lds_u32;
typedef __attribute__((address_space(1))) const uint32_t glob_u32;

#define D_DIM 128
#define NROWS 1000000
#define NSTRIPS (NROWS / 16)        // 62500 strips of 16 rows
#define MAIN_GRID 512               // 2 blocks/CU guaranteed resident
#define WAVES_TOTAL (MAIN_GRID * 4) // 2048 waves, ~30.5 strips/wave

// Exact-GELU via Abramowitz-Stegun 7.1.26 erf (max abs err 1.5e-7).
__device__ __forceinline__ float gelu_exact(float x) {
    float t = 0.70710678118654752f * x;     // x / sqrt(2)
    float a = fabsf(t);
    float d = __builtin_amdgcn_rcpf(fmaf(0.3275911f, a, 1.0f));
    float p = fmaf(1.061405429f, d, -1.453152027f);
    p = fmaf(p, d, 1.421413741f);
    p = fmaf(p, d, -0.284496736f);
    p = fmaf(p, d, 0.254829592f);
    p = p * d;
    float e = __builtin_amdgcn_exp2f(a * a * -1.4426950408889634f); // exp(-t^2)
    float erf_a = fmaf(-p, e, 1.0f);
    float erf_t = copysignf(erf_a, t);
    return 0.5f * x * (1.0f + erf_t);
}

// Prep, 1088 blocks x 256 threads:
//  blk 0..63   : swizzle W1[0:128][:] into bf16 MFMA B-frag order w1f
//  blk 64..1087: pre[g][n] = z_local[g].W1_mid[:,n] + z_meta.W1_hi[:,n] + b1[n]
//                (4 graphs per block; z staged in LDS; k-loop unrolled x8 so
//                 ~16 L2 loads stay in flight per thread -> latency hidden)
__global__ __launch_bounds__(256) void prep_all(
    const float* __restrict__ z_local, const float* __restrict__ z_meta,
    const float* __restrict__ W1, const float* __restrict__ b1,
    __bf16* __restrict__ w1f, float* __restrict__ pre) {
    const int blk = blockIdx.x;
    const int tid = threadIdx.x;
    if (blk < 64) {
        // frag f = ((kc*8+nt)*64+lane)*8+j holds W1[kc*32+(lane>>4)*8+j][nt*16+(lane&15)]
        int f = blk * 256 + tid;              // 16384 total
        int j = f & 7, lane = (f >> 3) & 63, nt = (f >> 9) & 7, kc = f >> 12;
        int k = kc * 32 + (lane >> 4) * 8 + j;
        int n = nt * 16 + (lane & 15);
        w1f[f] = (__bf16)W1[k * D_DIM + n];
    } else {
        __shared__ float zl[4][D_DIM];        // this block's 4 z_local rows
        __shared__ float zm[D_DIM];
        const int pb = blk - 64;              // 0..1023
        const int n = tid & 127;
        const int half = tid >> 7;
        for (int i = tid; i < 4 * D_DIM; i += 256)
            zl[i >> 7][i & 127] =
                z_local[(size_t)(pb * 4 + (i >> 7)) * D_DIM + (i & 127)];
        if (tid < D_DIM) zm[tid] = z_meta[tid];
        __syncthreads();

        float s0 = 0.f, s1 = 0.f, sm = b1[n];
        const float* wmid = W1 + (size_t)D_DIM * D_DIM + n;       // W1[128+k][n]
        const float* whi  = W1 + (size_t)2 * D_DIM * D_DIM + n;   // W1[256+k][n]
#pragma unroll 8
        for (int k = 0; k < D_DIM; ++k) {
            float wm = wmid[k * D_DIM];
            float wh = whi[k * D_DIM];
            s0 = fmaf(zl[half * 2][k],     wm, s0);
            s1 = fmaf(zl[half * 2 + 1][k], wm, s1);
            sm = fmaf(zm[k],               wh, sm);
        }
        const int g0 = pb * 4 + half * 2;
        pre[(size_t)g0 * D_DIM + n]       = s0 + sm;
        pre[(size_t)(g0 + 1) * D_DIM + n] = s1 + sm;
    }
}

// Main: persistent blocks, 4 waves each; wave = 16 rows x 128 cols per strip
// via 8x mfma_f32_16x16x32_bf16. w1s staged once; strips stream with a 2-deep
// register double buffer (aA/aB alternate) and no barriers inside the loop.
__global__ __launch_bounds__(256) void readout_main(
    const float* __restrict__ nodes, const int* __restrict__ batch,
    const float* __restrict__ pre, const __bf16* __restrict__ w1f,
    const float* __restrict__ W2, const float* __restrict__ b2,
    float* __restrict__ out) {
    __shared__ __bf16 w1s[16384];    // 32 KB, read-only after prologue
    const int tid = threadIdx.x;
    const int wave = tid >> 6;
    const int lane = tid & 63;
    const int q = lane >> 4;         // quad index
    const int c0 = lane & 15;

    // Stage w1f -> LDS once: wave w copies bytes [w*8KB, (w+1)*8KB).
    {
        const __bf16* gsrc = w1f + wave * 4096;
        __bf16* ldst = w1s + wave * 4096;
#pragma unroll
        for (int it = 0; it < 8; ++it) {
            __builtin_amdgcn_global_load_lds(
                (glob_u32*)(gsrc + it * 512 + lane * 8),
                (lds_u32*)(ldst + it * 512), 16, 0, 0);
        }
    }

    float w2v[8];
#pragma unroll
    for (int nt = 0; nt < 8; ++nt) w2v[nt] = W2[nt * 16 + c0];
    const float b2v = b2[0];

    const int wgid = blockIdx.x * 4 + wave;

    auto load_tile = [&](f32x4* a, int* br, int s) {
        const float* aptr = nodes + (size_t)(s * 16 + c0) * D_DIM + q * 8;
#pragma unroll
        for (int kc = 0; kc < 4; ++kc) {
            a[2 * kc]     = *((const f32x4*)(aptr + kc * 32));
            a[2 * kc + 1] = *((const f32x4*)(aptr + kc * 32 + 4));
        }
#pragma unroll
        for (int r = 0; r < 4; ++r) br[r] = batch[s * 16 + q * 4 + r];
    };

    auto compute_tile = [&](const f32x4* a, const int* br, int s) {
        f32x4 acc[8] = {};
        const bf16x8* bfr = (const bf16x8*)w1s;
#pragma unroll
        for (int kc = 0; kc < 4; ++kc) {
            bf16x8 af;
#pragma unroll
            for (int j = 0; j < 8; ++j)
                af[j] = (__bf16)a[2 * kc + (j >> 2)][j & 3];   // RNE fp32->bf16
#pragma unroll
            for (int nt = 0; nt < 8; ++nt) {
                bf16x8 bf = bfr[(kc * 8 + nt) * 64 + lane];    // ds_read_b128
                acc[nt] = __builtin_amdgcn_mfma_f32_16x16x32_bf16(af, bf, acc[nt], 0, 0, 0);
            }
        }
        // Epilogue: u = acc + pre[batch[row]][col]; logit = gelu(u).W2 + b2
        // C/D layout: col = c0 + 16*nt, row = q*4 + r
#pragma unroll
        for (int r = 0; r < 4; ++r) {
            const float* prow = pre + (size_t)br[r] * D_DIM;
            float partial = 0.f;
#pragma unroll
            for (int nt = 0; nt < 8; ++nt) {
                float u = acc[nt][r] + prow[nt * 16 + c0];
                partial += gelu_exact(u) * w2v[nt];
            }
            partial += __shfl_xor(partial, 1);
            partial += __shfl_xor(partial, 2);
            partial += __shfl_xor(partial, 4);
            partial += __shfl_xor(partial, 8);
            if (c0 == 0) out[s * 16 + q * 4 + r] = partial + b2v;
        }
    };

    f32x4 aA[8], aB[8];
    int brA[4], brB[4];
    int sA = wgid;                   // wgid < 2048 < NSTRIPS always valid
    load_tile(aA, brA, sA);
    __syncthreads();                 // drains global_load_lds + aA loads

    while (true) {
        int sB = sA + WAVES_TOTAL;
        load_tile(aB, brB, sB < NSTRIPS ? sB : wgid);  // clamped dummy at tail
        compute_tile(aA, brA, sA);
        if (sB >= NSTRIPS) break;
        int sC = sB + WAVES_TOTAL;
        load_tile(aA, brA, sC < NSTRIPS ? sC : wgid);
        compute_tile(aB, brB, sB);
        if (sC >= NSTRIPS) break;
        sA = sC;
    }
}

extern "C" void kernel_launch(void* const* d_in, const int* in_sizes, int n_in,
                              void* d_out, int out_size, void* d_ws, size_t ws_size,
                              hipStream_t stream) {
    const float* nodes   = (const float*)d_in[0];
    const float* z_local = (const float*)d_in[1];
    const float* z_meta  = (const float*)d_in[2];
    const float* W1      = (const float*)d_in[3];
    const float* b1      = (const float*)d_in[4];
    const float* W2      = (const float*)d_in[5];
    const float* b2      = (const float*)d_in[6];
    const int*   batch   = (const int*)d_in[7];
    float* out = (float*)d_out;

    char* ws = (char*)d_ws;
    __bf16* w1f = (__bf16*)ws;               // 16384 bf16 = 32 KB
    float* pre  = (float*)(ws + 32768);      // 4096*128 f32 = 2 MB (bias folded in)

    prep_all<<<1088, 256, 0, stream>>>(z_local, z_meta, W1, b1, w1f, pre);
    readout_main<<<MAIN_GRID, 256, 0, stream>>>(nodes, batch, pre, w1f, W2, b2, out);
}

// Round 3
// 690.622 us; speedup vs baseline: 1.0894x; 1.0894x over previous
//
#include <hip/hip_runtime.h>
#include <hip/hip_bf16.h>
#include <cstdint>

// Readout: logits = W2 . gelu(W1^T [nodes; z_local[batch]; z_meta] + b1) + b2
// Split GEMM: nodes@W1_lo via bf16 MFMA (memory-bound); z_local@W1_mid -> pre[B,128]
// (fp32 exact); z_meta@W1_hi + b1 -> bias2[128]. w1f staged in LDS per block.
// Readout processes 2 tiles (128 rows) per block: stage amortized 2x, tile-2 A
// prefetch issued under tile-1 compute, and the tile-1 pre-gather is issued
// BEFORE tile-2's A loads so the in-order vmcnt wait on p1 does not drain the
// prefetch. Straight-line code, named arrays, compile-time indices only.

typedef __attribute__((ext_vector_type(8))) __bf16 bf16x8;
typedef __attribute__((ext_vector_type(4))) float f32x4;
typedef __attribute__((address_space(3))) uint32_t lds_u32;
typedef __attribute__((address_space(1))) const uint32_t glob_u32;

#define D_DIM 128
#define NROWS 1000000

// Exact-GELU via Abramowitz-Stegun 7.1.26 erf (max abs err 1.5e-7).
__device__ __forceinline__ float gelu_exact(float x) {
    float t = 0.70710678118654752f * x;     // x / sqrt(2)
    float a = fabsf(t);
    float d = __builtin_amdgcn_rcpf(fmaf(0.3275911f, a, 1.0f));
    float p = fmaf(1.061405429f, d, -1.453152027f);
    p = fmaf(p, d, 1.421413741f);
    p = fmaf(p, d, -0.284496736f);
    p = fmaf(p, d, 0.254829592f);
    p = p * d;
    float e = __builtin_amdgcn_exp2f(a * a * -1.4426950408889634f); // exp(-t^2)
    float erf_a = fmaf(-p, e, 1.0f);
    float erf_t = copysignf(erf_a, t);
    return 0.5f * x * (1.0f + erf_t);
}

// One prep kernel, 577 blocks x 256 threads, all parts independent:
//  blk 0..63  : swizzle W1[0:128][:] into bf16 MFMA B-frag order w1f
//  blk 64     : bias2[n] = b1[n] + z_meta . W1[256:384][n]
//  blk 65..576: pre[b][n] = z_local[b] . W1[128:256][n]   (NO bias2 here)
__global__ __launch_bounds__(256) void prep_all(
    const float* __restrict__ z_local, const float* __restrict__ z_meta,
    const float* __restrict__ W1, const float* __restrict__ b1,
    __bf16* __restrict__ w1f, float* __restrict__ bias2, float* __restrict__ pre) {
    const int blk = blockIdx.x;
    const int tid = threadIdx.x;
    if (blk < 64) {
        // frag f = ((kc*8+nt)*64+lane)*8+j holds W1[kc*32+(lane>>4)*8+j][nt*16+(lane&15)]
        int f = blk * 256 + tid;              // 16384 total
        int j = f & 7, lane = (f >> 3) & 63, nt = (f >> 9) & 7, kc = f >> 12;
        int k = kc * 32 + (lane >> 4) * 8 + j;
        int n = nt * 16 + (lane & 15);
        w1f[f] = (__bf16)W1[k * D_DIM + n];
    } else if (blk == 64) {
        if (tid < D_DIM) {
            int n = tid;
            float s = b1[n];
            for (int k = 0; k < D_DIM; ++k)
                s = fmaf(z_meta[k], W1[(2 * D_DIM + k) * D_DIM + n], s);
            bias2[n] = s;
        }
    } else {
        int pb = blk - 65;                    // 0..511
        int n = tid & 127;
        int g0 = pb * 8 + (tid >> 7) * 4;     // 4 graphs per half-block
        float s[4] = {0.f, 0.f, 0.f, 0.f};
        for (int k = 0; k < D_DIM; ++k) {
            float wk = W1[(D_DIM + k) * D_DIM + n];
#pragma unroll
            for (int g = 0; g < 4; ++g)
                s[g] = fmaf(z_local[(size_t)(g0 + g) * D_DIM + k], wk, s[g]);
        }
#pragma unroll
        for (int g = 0; g < 4; ++g) pre[(size_t)(g0 + g) * D_DIM + n] = s[g];
    }
}

// Main: block=256 (4 waves); each wave = 16 rows x 128 cols per tile via
// 8x mfma_f32_16x16x32_bf16; TWO tiles per block (rows blk*128 .. +127).
__global__ __launch_bounds__(256) void readout_main(
    const float* __restrict__ nodes, const int* __restrict__ batch,
    const float* __restrict__ pre, const __bf16* __restrict__ w1f,
    const float* __restrict__ bias2, const float* __restrict__ W2,
    const float* __restrict__ b2, float* __restrict__ out) {
    __shared__ __bf16 w1s[16384];    // 32 KB
    const int tid = threadIdx.x;
    const int wave = tid >> 6;
    const int lane = tid & 63;
    const int q = lane >> 4;         // quad index
    const int c0 = lane & 15;
    const int row1 = blockIdx.x * 128 + wave * 16;
    const int row2 = row1 + 64;
    const bool has2 = (blockIdx.x < (NROWS / 128));   // block-uniform tail guard

    // Tile-1 A loads (16 rows x 128 k, fp32, 16B/lane) issued first.
    const float* aptr1 = nodes + (size_t)(row1 + c0) * D_DIM + q * 8;
    f32x4 a1[8];
#pragma unroll
    for (int kc = 0; kc < 4; ++kc) {
        a1[2 * kc]     = *((const f32x4*)(aptr1 + kc * 32));
        a1[2 * kc + 1] = *((const f32x4*)(aptr1 + kc * 32 + 4));
    }
    int br1[4];
#pragma unroll
    for (int r = 0; r < 4; ++r) br1[r] = batch[row1 + q * 4 + r];

    // Stage w1f -> LDS: wave w copies bytes [w*8KB, (w+1)*8KB), 16B/lane/call.
    {
        const __bf16* gsrc = w1f + wave * 4096;
        __bf16* ldst = w1s + wave * 4096;
#pragma unroll
        for (int it = 0; it < 8; ++it) {
            __builtin_amdgcn_global_load_lds(
                (glob_u32*)(gsrc + it * 512 + lane * 8),
                (lds_u32*)(ldst + it * 512), 16, 0, 0);
        }
    }

    float w2v[8], bz[8];
#pragma unroll
    for (int nt = 0; nt < 8; ++nt) {
        w2v[nt] = W2[nt * 16 + c0];
        bz[nt]  = bias2[nt * 16 + c0];
    }
    const float b2v = b2[0];

    __syncthreads();   // drains global_load_lds (vmcnt) + barrier

    // P1 gather issued BEFORE tile-2 A loads: in-order vmcnt means epi-1's wait
    // on p1 then leaves the tile-2 prefetch outstanding.
    float p1[4][8];
#pragma unroll
    for (int r = 0; r < 4; ++r) {
        const float* prow = pre + (size_t)br1[r] * D_DIM;
#pragma unroll
        for (int nt = 0; nt < 8; ++nt) p1[r][nt] = prow[nt * 16 + c0];
    }

    // Tile-2 A + batch prefetch (latency hidden under tile-1 compute/epilogue).
    f32x4 a2[8];
    int br2[4];
    if (has2) {
        const float* aptr2 = nodes + (size_t)(row2 + c0) * D_DIM + q * 8;
#pragma unroll
        for (int kc = 0; kc < 4; ++kc) {
            a2[2 * kc]     = *((const f32x4*)(aptr2 + kc * 32));
            a2[2 * kc + 1] = *((const f32x4*)(aptr2 + kc * 32 + 4));
        }
#pragma unroll
        for (int r = 0; r < 4; ++r) br2[r] = batch[row2 + q * 4 + r];
    }

    const bf16x8* bfr = (const bf16x8*)w1s;

    // ---- tile 1: MFMA ----
    f32x4 acc[8] = {};
#pragma unroll
    for (int kc = 0; kc < 4; ++kc) {
        bf16x8 af;
#pragma unroll
        for (int j = 0; j < 8; ++j)
            af[j] = (__bf16)a1[2 * kc + (j >> 2)][j & 3];   // RNE fp32->bf16
#pragma unroll
        for (int nt = 0; nt < 8; ++nt) {
            bf16x8 bf = bfr[(kc * 8 + nt) * 64 + lane];     // ds_read_b128
            acc[nt] = __builtin_amdgcn_mfma_f32_16x16x32_bf16(af, bf, acc[nt], 0, 0, 0);
        }
    }
    // ---- tile 1: epilogue (C/D layout: col = c0 + 16*nt, row = q*4 + r) ----
#pragma unroll
    for (int r = 0; r < 4; ++r) {
        float partial = 0.f;
#pragma unroll
        for (int nt = 0; nt < 8; ++nt) {
            float u = acc[nt][r] + p1[r][nt] + bz[nt];
            partial += gelu_exact(u) * w2v[nt];
        }
        partial += __shfl_xor(partial, 1);
        partial += __shfl_xor(partial, 2);
        partial += __shfl_xor(partial, 4);
        partial += __shfl_xor(partial, 8);
        if (c0 == 0) out[row1 + q * 4 + r] = partial + b2v;
    }

    if (!has2) return;

    // P2 gather (reuses p1 registers; issued as soon as epi-1 consumed them).
#pragma unroll
    for (int r = 0; r < 4; ++r) {
        const float* prow = pre + (size_t)br2[r] * D_DIM;
#pragma unroll
        for (int nt = 0; nt < 8; ++nt) p1[r][nt] = prow[nt * 16 + c0];
    }

    // ---- tile 2: MFMA ----
#pragma unroll
    for (int nt = 0; nt < 8; ++nt) acc[nt] = (f32x4){0.f, 0.f, 0.f, 0.f};
#pragma unroll
    for (int kc = 0; kc < 4; ++kc) {
        bf16x8 af;
#pragma unroll
        for (int j = 0; j < 8; ++j)
            af[j] = (__bf16)a2[2 * kc + (j >> 2)][j & 3];
#pragma unroll
        for (int nt = 0; nt < 8; ++nt) {
            bf16x8 bf = bfr[(kc * 8 + nt) * 64 + lane];
            acc[nt] = __builtin_amdgcn_mfma_f32_16x16x32_bf16(af, bf, acc[nt], 0, 0, 0);
        }
    }
    // ---- tile 2: epilogue ----
#pragma unroll
    for (int r = 0; r < 4; ++r) {
        float partial = 0.f;
#pragma unroll
        for (int nt = 0; nt < 8; ++nt) {
            float u = acc[nt][r] + p1[r][nt] + bz[nt];
            partial += gelu_exact(u) * w2v[nt];
        }
        partial += __shfl_xor(partial, 1);
        partial += __shfl_xor(partial, 2);
        partial += __shfl_xor(partial, 4);
        partial += __shfl_xor(partial, 8);
        if (c0 == 0) out[row2 + q * 4 + r] = partial + b2v;
    }
}

extern "C" void kernel_launch(void* const* d_in, const int* in_sizes, int n_in,
                              void* d_out, int out_size, void* d_ws, size_t ws_size,
                              hipStream_t stream) {
    const float* nodes   = (const float*)d_in[0];
    const float* z_local = (const float*)d_in[1];
    const float* z_meta  = (const float*)d_in[2];
    const float* W1      = (const float*)d_in[3];
    const float* b1      = (const float*)d_in[4];
    const float* W2      = (const float*)d_in[5];
    const float* b2      = (const float*)d_in[6];
    const int*   batch   = (const int*)d_in[7];
    float* out = (float*)d_out;

    char* ws = (char*)d_ws;
    __bf16* w1f  = (__bf16*)ws;              // 16384 bf16 = 32 KB
    float* bias2 = (float*)(ws + 32768);     // 128 f32
    float* pre   = (float*)(ws + 33280);     // 4096*128 f32 = 2 MB

    prep_all<<<577, 256, 0, stream>>>(z_local, z_meta, W1, b1, w1f, bias2, pre);
    // 1e6 rows, 128 rows/block -> 7813 blocks (last block: tile 1 only)
    readout_main<<<7813, 256, 0, stream>>>(nodes, batch, pre, w1f, bias2, W2, b2, out);
}